// Round 13
// baseline (109.158 us; speedup 1.0000x reference)
//
#include <hip/hip_runtime.h>

#define NN 50000
#define NE 800000
#define DIN 96
#define DH 128
#define DOUT 16
#define NBKT ((NN + 127) / 128)     // 391 buckets of 128 nodes
#define CAPB 2560                    // max edges per bucket (mean 2048 + 11 sigma)
#define EPB 8192                     // edges per phase-A block
#define NSLC ((NE + EPB - 1) / EPB)  // 98 phase-A blocks = slices per bucket
#define SLICE 52                     // per-slice capacity (mean 21 + 6.8 sigma)

typedef __attribute__((ext_vector_type(8))) short bf16x8;
typedef __attribute__((ext_vector_type(4))) float f32x4;
typedef unsigned short ushort_t;

__device__ inline short f2bf(float f) {
    unsigned u = __float_as_uint(f);
    u += 0x7fff + ((u >> 16) & 1);          // round-to-nearest-even
    return (short)(u >> 16);
}
__device__ inline float bflo(unsigned u) { return __uint_as_float(u << 16); }
__device__ inline float bfhi(unsigned u) { return __uint_as_float(u & 0xffff0000u); }

// ================= K1: fused cast-x / cast-weights / slice-bucketed scatter =================
#define XB_BLOCKS ((NN * DIN / 4 + 511) / 512)               // 2344
#define WC_BLOCKS ((DH * 192 + 32 * DH + 511) / 512)         // 56
__global__ __launch_bounds__(512) void k_prep(const float* __restrict__ x,
                                              const float* __restrict__ W1l,
                                              const float* __restrict__ W1r,
                                              const float* __restrict__ W2l,
                                              const float* __restrict__ W2r,
                                              const int* __restrict__ ei,
                                              short* __restrict__ xb,
                                              short* __restrict__ Bt,
                                              short* __restrict__ Bt2,
                                              unsigned* __restrict__ bpack,
                                              int* __restrict__ scnt) {
    __shared__ unsigned stage[EPB];     // 32 KB
    __shared__ int bcnt[NBKT];
    __shared__ int bfil[NBKT];
    __shared__ int brun[NBKT];
    __shared__ int sbuf[512];
    const int tid = threadIdx.x;

    if (blockIdx.x < XB_BLOCKS) {
        int i = blockIdx.x * 512 + tid;
        if (i < NN * DIN / 4) {
            float4 v = ((const float4*)x)[i];
            short4 o;
            o.x = f2bf(v.x); o.y = f2bf(v.y); o.z = f2bf(v.z); o.w = f2bf(v.w);
            ((short4*)xb)[i] = o;
        }
        return;
    }
    if (blockIdx.x < XB_BLOCKS + WC_BLOCKS) {
        int idx = (blockIdx.x - XB_BLOCKS) * 512 + tid;
        if (idx < DH * 192) {
            int n = idx / 192, kk = idx % 192;
            float v = (kk < DIN) ? W1l[kk * DH + n] : W1r[(kk - DIN) * DH + n];
            Bt[idx] = f2bf(v);
        } else if (idx < DH * 192 + 32 * DH) {
            int j = idx - DH * 192;
            int c = j >> 7, k = j & 127;
            float v = (c < DOUT) ? W2l[k * DOUT + c] : W2r[k * DOUT + (c - DOUT)];
            Bt2[j] = f2bf(v);
        }
        return;
    }
    // ---- bucket-scatter block j ----
    const int j = blockIdx.x - XB_BLOCKS - WC_BLOCKS;
    const int e0 = j * EPB;
    const int ecnt = min(EPB, NE - e0);
    for (int i = tid; i < NBKT; i += 512) { bcnt[i] = 0; bfil[i] = 0; }
    __syncthreads();
    unsigned dcache[EPB / 512];
#pragma unroll
    for (int k = 0; k < EPB / 512; ++k) {
        int i = tid + k * 512;
        if (i < ecnt) {
            unsigned d = (unsigned)ei[NE + e0 + i];
            dcache[k] = d;
            atomicAdd(&bcnt[d >> 7], 1);
        }
    }
    __syncthreads();
    int v = (tid < NBKT) ? bcnt[tid] : 0;
    sbuf[tid] = v;
    __syncthreads();
    for (int o = 1; o < 512; o <<= 1) {
        int tv = (tid >= o) ? sbuf[tid - o] : 0;
        __syncthreads();
        sbuf[tid] += tv;
        __syncthreads();
    }
    if (tid < NBKT) brun[tid] = sbuf[tid] - v;
    __syncthreads();
#pragma unroll
    for (int k = 0; k < EPB / 512; ++k) {
        int i = tid + k * 512;
        if (i < ecnt) {
            unsigned s = (unsigned)ei[e0 + i];
            unsigned d = dcache[k];
            int b = d >> 7;
            int p = atomicAdd(&bfil[b], 1);
            stage[brun[b] + p] = (d << 16) | s;
        }
    }
    __syncthreads();
    for (int i = tid; i < ecnt; i += 512) {
        unsigned p = stage[i];
        int b = p >> 23;
        int idx = i - brun[b];
        if (idx < SLICE)
            bpack[((size_t)b * NSLC + j) * SLICE + idx] = p;
    }
    for (int b = tid; b < NBKT; b += 512)
        scnt[b * NSLC + j] = min(bcnt[b], SLICE);
}

// ================= K2: per-bucket compact + extents + gather-mean + lin1 + proj =================
__global__ __launch_bounds__(512) void k_mega(const short* __restrict__ xb,
                                              const unsigned* __restrict__ bpack,
                                              const int* __restrict__ scnt,
                                              const short* __restrict__ Bt,
                                              const float* __restrict__ b1,
                                              const short* __restrict__ Bt2,
                                              const float* __restrict__ b2,
                                              int* __restrict__ offs,
                                              int* __restrict__ offe,
                                              ushort_t* __restrict__ csr,
                                              short* __restrict__ zlb,
                                              float* __restrict__ sout) {
    __shared__ __align__(16) char uscr[128 * 136 * 2];  // pairs[2560] (10KB)  U  ht[128][136] (34.8KB)
    unsigned* pairs = (unsigned*)uscr;
    short (*ht)[136] = (short(*)[136])uscr;
    __shared__ __align__(16) short m1t[128][104];       // 26.6 KB, pad 104 for conflict-free b128
    __shared__ ushort_t csr_l[CAPB];                    // 5 KB
    __shared__ int scl[NSLC];
    __shared__ int sbs[NSLC];
    __shared__ int sbuf[512];
    __shared__ int ncnt[128];
    __shared__ int nrun[128];
    __shared__ int lcur[128];
    __shared__ float inv_l[128];
    __shared__ int cnt_s;

    const int b = blockIdx.x;
    const int tid = threadIdx.x;
    const int w = tid >> 6;
    const int l = tid & 63;

    // --- slice counts + scan ---
    if (tid < NSLC) scl[tid] = scnt[b * NSLC + tid];
    __syncthreads();
    int v = (tid < NSLC) ? scl[tid] : 0;
    sbuf[tid] = v;
    __syncthreads();
    for (int o = 1; o < 512; o <<= 1) {
        int tv = (tid >= o) ? sbuf[tid - o] : 0;
        __syncthreads();
        sbuf[tid] += tv;
        __syncthreads();
    }
    if (tid < NSLC) sbs[tid] = sbuf[tid] - v;
    if (tid == NSLC - 1) cnt_s = sbuf[tid];
    if (tid < 128) { ncnt[tid] = 0; lcur[tid] = 0; }
    __syncthreads();
    const int cnt = min(cnt_s, CAPB);

    // --- compact slices into pairs ---
    for (int idx = tid; idx < NSLC * SLICE; idx += 512) {
        int j = idx / SLICE, k = idx - j * SLICE;
        if (k < scl[j]) {
            int pos = sbs[j] + k;
            if (pos < CAPB)
                pairs[pos] = bpack[((size_t)b * NSLC + j) * SLICE + k];
        }
    }
    __syncthreads();

    // --- per-node histogram + scan ---
    for (int i = tid; i < cnt; i += 512)
        atomicAdd(&ncnt[(pairs[i] >> 16) & 127], 1);
    __syncthreads();
    v = (tid < 128) ? ncnt[tid] : 0;
    sbuf[tid] = v;
    __syncthreads();
    for (int o = 1; o < 512; o <<= 1) {
        int tv = (tid >= o) ? sbuf[tid - o] : 0;
        __syncthreads();
        sbuf[tid] += tv;
        __syncthreads();
    }
    if (tid < 128) {
        nrun[tid] = sbuf[tid] - v;
        inv_l[tid] = v ? 1.0f / (float)v : 0.0f;
        const int n = b * 128 + tid;
        if (n < NN) {
            offs[n] = b * CAPB + nrun[tid];
            offe[n] = b * CAPB + nrun[tid] + v;
        }
    }
    __syncthreads();

    // --- rank-fill csr_l ---
    for (int i = tid; i < cnt; i += 512) {
        unsigned p = pairs[i];
        int nd = (p >> 16) & 127;
        int pos = atomicAdd(&lcur[nd], 1);
        csr_l[nrun[nd] + pos] = (ushort_t)(p & 0xffffu);
    }
    __syncthreads();

    // --- mirror csr_l to global (for agg2) ---
    for (int i = tid; i < CAPB / 2; i += 512)
        ((int*)csr)[(size_t)b * (CAPB / 2) + i] = ((const int*)csr_l)[i];

    // --- gather-mean into m1t: wave w handles nodes w, w+8, ... ---
    {
        const int eg = l / 12;
        const int c  = l % 12;
        const float4* xq = (const float4*)xb;   // row = 12 float4
        for (int nd = w; nd < 128; nd += 8) {
            const int bl = nrun[nd];
            const int deg = ncnt[nd];
            float acc[8];
#pragma unroll
            for (int k = 0; k < 8; ++k) acc[k] = 0.f;
            int i = (eg < 4) ? eg : deg;
            for (; i + 12 < deg; i += 16) {
                int s0 = csr_l[bl + i], s1 = csr_l[bl + i + 4];
                int s2 = csr_l[bl + i + 8], s3 = csr_l[bl + i + 12];
                float4 v0 = xq[(size_t)s0 * 12 + c];
                float4 v1 = xq[(size_t)s1 * 12 + c];
                float4 v2 = xq[(size_t)s2 * 12 + c];
                float4 v3 = xq[(size_t)s3 * 12 + c];
                const unsigned* u0 = (const unsigned*)&v0;
                const unsigned* u1 = (const unsigned*)&v1;
                const unsigned* u2 = (const unsigned*)&v2;
                const unsigned* u3 = (const unsigned*)&v3;
#pragma unroll
                for (int jj = 0; jj < 4; ++jj) {
                    acc[2 * jj]     += (bflo(u0[jj]) + bflo(u1[jj])) + (bflo(u2[jj]) + bflo(u3[jj]));
                    acc[2 * jj + 1] += (bfhi(u0[jj]) + bfhi(u1[jj])) + (bfhi(u2[jj]) + bfhi(u3[jj]));
                }
            }
            for (; i < deg; i += 4) {
                float4 v0 = xq[(size_t)csr_l[bl + i] * 12 + c];
                const unsigned* u0 = (const unsigned*)&v0;
#pragma unroll
                for (int jj = 0; jj < 4; ++jj) {
                    acc[2 * jj]     += bflo(u0[jj]);
                    acc[2 * jj + 1] += bfhi(u0[jj]);
                }
            }
#pragma unroll
            for (int k = 0; k < 8; ++k) acc[k] += __shfl(acc[k], l + 24);
#pragma unroll
            for (int k = 0; k < 8; ++k) acc[k] += __shfl(acc[k], l + 12);
            if (l < 12) {
                const float inv = inv_l[nd];
                uint4 o;
                unsigned* op = (unsigned*)&o;
#pragma unroll
                for (int jj = 0; jj < 4; ++jj)
                    op[jj] = (unsigned)(unsigned short)f2bf(acc[2 * jj] * inv)
                           | ((unsigned)(unsigned short)f2bf(acc[2 * jj + 1] * inv) << 16);
                *(uint4*)&m1t[nd][c * 8] = o;
            }
        }
    }
    __syncthreads();

    // --- lin1 MFMA: 8 waves x 16 rows ---
    const int lr = l & 15;
    const int lk = l >> 4;
    int row_g = b * 128 + w * 16 + lr;
    if (row_g >= NN) row_g = NN - 1;

    f32x4 acc1[8];
#pragma unroll
    for (int nt = 0; nt < 8; ++nt) {
        float bv = b1[nt * 16 + lr];
        acc1[nt] = (f32x4){bv, bv, bv, bv};
    }
    bf16x8 afr[6];
    {
        const bf16x8* am = (const bf16x8*)&m1t[w * 16 + lr][0];
        const bf16x8* ax = (const bf16x8*)(xb + (size_t)row_g * DIN);
        afr[0] = am[lk];     afr[1] = am[4 + lk]; afr[2] = am[8 + lk];
        afr[3] = ax[lk];     afr[4] = ax[4 + lk]; afr[5] = ax[8 + lk];
    }
    const bf16x8* bt8 = (const bf16x8*)Bt;
#pragma unroll
    for (int st = 0; st < 6; ++st) {
#pragma unroll
        for (int nt = 0; nt < 8; ++nt) {
            bf16x8 bfr = bt8[(size_t)(nt * 16 + lr) * 24 + st * 4 + lk];
            acc1[nt] = __builtin_amdgcn_mfma_f32_16x16x32_bf16(afr[st], bfr, acc1[nt], 0, 0, 0);
        }
    }
    __syncthreads();     // pairs region dead; safe to overwrite as ht
    const int lrow0 = w * 16 + lk * 4;
#pragma unroll
    for (int r = 0; r < 4; ++r) {
#pragma unroll
        for (int nt = 0; nt < 8; ++nt)
            ht[lrow0 + r][nt * 16 + lr] = f2bf(fmaxf(acc1[nt][r], 0.f));
    }
    __syncthreads();

    // --- proj MFMA ---
    bf16x8 pafr[4];
#pragma unroll
    for (int st = 0; st < 4; ++st)
        pafr[st] = *(const bf16x8*)&ht[w * 16 + lr][st * 32 + lk * 8];

    f32x4 accz = (f32x4){0.f, 0.f, 0.f, 0.f};
    float bv = b2[lr];
    f32x4 accs = (f32x4){bv, bv, bv, bv};
    const bf16x8* b8 = (const bf16x8*)Bt2;
#pragma unroll
    for (int st = 0; st < 4; ++st) {
        bf16x8 bz = b8[(size_t)lr * 16 + st * 4 + lk];
        bf16x8 bs = b8[(size_t)(16 + lr) * 16 + st * 4 + lk];
        accz = __builtin_amdgcn_mfma_f32_16x16x32_bf16(pafr[st], bz, accz, 0, 0, 0);
        accs = __builtin_amdgcn_mfma_f32_16x16x32_bf16(pafr[st], bs, accs, 0, 0, 0);
    }
    const int orow0 = b * 128 + w * 16 + lk * 4;
#pragma unroll
    for (int r = 0; r < 4; ++r) {
        const int orow = orow0 + r;
        if (orow < NN) {
            zlb[(size_t)orow * DOUT + lr] = f2bf(accz[r]);
            sout[(size_t)orow * DOUT + lr] = accs[r];
        }
    }
}

// ================= K3: agg2 + softmax =================
__global__ __launch_bounds__(256) void k_agg2(const short* __restrict__ zlb,
                                              const float* __restrict__ s,
                                              const ushort_t* __restrict__ csr,
                                              const int* __restrict__ offs,
                                              const int* __restrict__ offe,
                                              float* __restrict__ out) {
    const int w = threadIdx.x >> 6;
    const int lane = threadIdx.x & 63;
    const int n = blockIdx.x * 4 + w;
    if (n >= NN) return;
    const int b = offs[n], e = offe[n];
    const int ng = lane >> 2;
    const int sl = lane & 3;
    const uint2* z2 = (const uint2*)zlb;
    float4 acc = {0.f, 0.f, 0.f, 0.f};
    for (int i = b + ng; i < e; i += 16) {
        uint2 u = z2[(size_t)csr[i] * 4 + sl];
        acc.x += bflo(u.x);
        acc.y += bfhi(u.x);
        acc.z += bflo(u.y);
        acc.w += bfhi(u.y);
    }
#pragma unroll
    for (int o = 4; o <= 32; o <<= 1) {
        acc.x += __shfl_xor(acc.x, o);
        acc.y += __shfl_xor(acc.y, o);
        acc.z += __shfl_xor(acc.z, o);
        acc.w += __shfl_xor(acc.w, o);
    }
    const float inv = (e > b) ? 1.0f / (float)(e - b) : 0.0f;
    const float4 sv = ((const float4*)s)[(size_t)n * 4 + sl];
    float4 v;
    v.x = acc.x * inv + sv.x;
    v.y = acc.y * inv + sv.y;
    v.z = acc.z * inv + sv.z;
    v.w = acc.w * inv + sv.w;
    float mx = fmaxf(fmaxf(v.x, v.y), fmaxf(v.z, v.w));
    mx = fmaxf(mx, __shfl_xor(mx, 1));
    mx = fmaxf(mx, __shfl_xor(mx, 2));
    v.x = expf(v.x - mx); v.y = expf(v.y - mx);
    v.z = expf(v.z - mx); v.w = expf(v.w - mx);
    float sm = v.x + v.y + v.z + v.w;
    sm += __shfl_xor(sm, 1);
    sm += __shfl_xor(sm, 2);
    const float r = 1.0f / sm;
    v.x *= r; v.y *= r; v.z *= r; v.w *= r;
    if (ng == 0) ((float4*)out)[(size_t)n * 4 + sl] = v;
}

template <typename T>
static inline T* align_up(void* p, size_t a = 64) {
    return (T*)(((uintptr_t)p + (a - 1)) & ~(uintptr_t)(a - 1));
}

extern "C" void kernel_launch(void* const* d_in, const int* in_sizes, int n_in,
                              void* d_out, int out_size, void* d_ws, size_t ws_size,
                              hipStream_t stream) {
    const float* x   = (const float*)d_in[0];
    const int*   ei  = (const int*)d_in[1];
    const float* W1l = (const float*)d_in[2];
    const float* b1  = (const float*)d_in[3];
    const float* W1r = (const float*)d_in[4];
    const float* W2l = (const float*)d_in[5];
    const float* b2  = (const float*)d_in[6];
    const float* W2r = (const float*)d_in[7];
    float* out = (float*)d_out;

    // workspace layout
    unsigned* bpack = (unsigned*)d_ws;                                 // NBKT*NSLC*SLICE (~8MB)
    int* scnt     = (int*)(bpack + (size_t)NBKT * NSLC * SLICE);       // NBKT*NSLC
    float* s      = (float*)(scnt + (size_t)NBKT * NSLC);              // NN*DOUT
    int* offs     = (int*)(s + (size_t)NN * DOUT);                     // NN
    int* offe     = offs + NN;                                         // NN
    ushort_t* csr = (ushort_t*)align_up<short>(offe + NN);             // NBKT*CAPB (2B)
    short* xb     = (short*)csr + (size_t)NBKT * CAPB;                 // NN*DIN
    short* zlb    = xb + (size_t)NN * DIN;                             // NN*DOUT
    short* Bt     = zlb + (size_t)NN * DOUT;                           // DH*192
    short* Bt2    = Bt + (size_t)DH * 192;                             // 32*DH

    k_prep<<<XB_BLOCKS + WC_BLOCKS + NSLC, 512, 0, stream>>>(
        x, W1l, W1r, W2l, W2r, ei, xb, Bt, Bt2, bpack, scnt);
    k_mega<<<NBKT, 512, 0, stream>>>(xb, bpack, scnt, Bt, b1, Bt2, b2,
                                     offs, offe, csr, zlb, s);
    k_agg2<<<(NN + 3) / 4, 256, 0, stream>>>(zlb, s, csr, offs, offe, out);
}

// Round 14
// 108.952 us; speedup vs baseline: 1.0019x; 1.0019x over previous
//
#include <hip/hip_runtime.h>

#define NN 50000
#define NE 800000
#define DIN 96
#define DH 128
#define DOUT 16
#define NBKT ((NN + 127) / 128)     // 391 buckets of 128 nodes
#define CAPB 2560                    // max edges per bucket (mean 2048 + 11 sigma)
#define EPB 2048                     // edges per scatter block
#define NSLC ((NE + EPB - 1) / EPB)  // 391 scatter blocks = slices per bucket
#define SLICE 24                     // per-(slice,bucket) capacity (mean 5.24, P(>=24)~2e-12)

typedef __attribute__((ext_vector_type(8))) short bf16x8;
typedef __attribute__((ext_vector_type(4))) float f32x4;
typedef unsigned short ushort_t;

__device__ inline short f2bf(float f) {
    unsigned u = __float_as_uint(f);
    u += 0x7fff + ((u >> 16) & 1);          // round-to-nearest-even
    return (short)(u >> 16);
}
__device__ inline float bflo(unsigned u) { return __uint_as_float(u << 16); }
__device__ inline float bfhi(unsigned u) { return __uint_as_float(u & 0xffff0000u); }

// ================= K1: fused cast-x / cast-weights / wide slice scatter =================
#define XB_BLOCKS ((NN * DIN / 4 + 511) / 512)               // 2344
#define WC_BLOCKS ((DH * 192 + 32 * DH + 511) / 512)         // 56
__global__ __launch_bounds__(512) void k_prep(const float* __restrict__ x,
                                              const float* __restrict__ W1l,
                                              const float* __restrict__ W1r,
                                              const float* __restrict__ W2l,
                                              const float* __restrict__ W2r,
                                              const int* __restrict__ ei,
                                              short* __restrict__ xb,
                                              short* __restrict__ Bt,
                                              short* __restrict__ Bt2,
                                              unsigned* __restrict__ bpack,
                                              int* __restrict__ scnt) {
    __shared__ unsigned stage[EPB];     // 8 KB
    __shared__ int bcnt[NBKT];
    __shared__ int bfil[NBKT];
    __shared__ int brun[NBKT];
    __shared__ int sbuf[512];
    const int tid = threadIdx.x;

    if (blockIdx.x < XB_BLOCKS) {
        int i = blockIdx.x * 512 + tid;
        if (i < NN * DIN / 4) {
            float4 v = ((const float4*)x)[i];
            short4 o;
            o.x = f2bf(v.x); o.y = f2bf(v.y); o.z = f2bf(v.z); o.w = f2bf(v.w);
            ((short4*)xb)[i] = o;
        }
        return;
    }
    if (blockIdx.x < XB_BLOCKS + WC_BLOCKS) {
        int idx = (blockIdx.x - XB_BLOCKS) * 512 + tid;
        if (idx < DH * 192) {
            int n = idx / 192, kk = idx % 192;
            float v = (kk < DIN) ? W1l[kk * DH + n] : W1r[(kk - DIN) * DH + n];
            Bt[idx] = f2bf(v);
        } else if (idx < DH * 192 + 32 * DH) {
            int j = idx - DH * 192;
            int c = j >> 7, k = j & 127;
            float v = (c < DOUT) ? W2l[k * DOUT + c] : W2r[k * DOUT + (c - DOUT)];
            Bt2[j] = f2bf(v);
        }
        return;
    }
    // ---- scatter block j: 2048 edges into per-(slice,bucket) runs ----
    const int j = blockIdx.x - XB_BLOCKS - WC_BLOCKS;
    const int e0 = j * EPB;
    const int ecnt = min(EPB, NE - e0);
    for (int i = tid; i < NBKT; i += 512) { bcnt[i] = 0; bfil[i] = 0; }
    __syncthreads();
    unsigned dcache[EPB / 512];
#pragma unroll
    for (int k = 0; k < EPB / 512; ++k) {
        int i = tid + k * 512;
        if (i < ecnt) {
            unsigned d = (unsigned)ei[NE + e0 + i];
            dcache[k] = d;
            atomicAdd(&bcnt[d >> 7], 1);
        }
    }
    __syncthreads();
    int v = (tid < NBKT) ? bcnt[tid] : 0;
    sbuf[tid] = v;
    __syncthreads();
    for (int o = 1; o < 512; o <<= 1) {
        int tv = (tid >= o) ? sbuf[tid - o] : 0;
        __syncthreads();
        sbuf[tid] += tv;
        __syncthreads();
    }
    if (tid < NBKT) brun[tid] = sbuf[tid] - v;
    __syncthreads();
#pragma unroll
    for (int k = 0; k < EPB / 512; ++k) {
        int i = tid + k * 512;
        if (i < ecnt) {
            unsigned s = (unsigned)ei[e0 + i];
            unsigned d = dcache[k];
            int b = d >> 7;
            int p = atomicAdd(&bfil[b], 1);
            stage[brun[b] + p] = (d << 16) | s;
        }
    }
    __syncthreads();
    for (int i = tid; i < ecnt; i += 512) {
        unsigned p = stage[i];
        int b = p >> 23;
        int idx = i - brun[b];
        if (idx < SLICE)
            bpack[((size_t)j * NBKT + b) * SLICE + idx] = p;
    }
    for (int b = tid; b < NBKT; b += 512)
        scnt[j * NBKT + b] = min(bcnt[b], SLICE);
}

// ================= K2: per-bucket compact + extents + csr fill =================
__global__ __launch_bounds__(512) void k_build(const unsigned* __restrict__ bpack,
                                               const int* __restrict__ scnt,
                                               int* __restrict__ offs,
                                               int* __restrict__ offe,
                                               ushort_t* __restrict__ csr) {
    __shared__ unsigned pairs[CAPB];    // 10 KB
    __shared__ int scl[NSLC];
    __shared__ int sbs[NSLC];
    __shared__ int sbuf[512];
    __shared__ int ncnt[128];
    __shared__ int nrun[128];
    __shared__ int lcur[128];
    __shared__ int cnt_s;
    const int bkt = blockIdx.x;
    const int tid = threadIdx.x;

    for (int j = tid; j < NSLC; j += 512) scl[j] = scnt[j * NBKT + bkt];
    if (tid < 128) { ncnt[tid] = 0; lcur[tid] = 0; }
    __syncthreads();
    int v = (tid < NSLC) ? scl[tid] : 0;
    sbuf[tid] = v;
    __syncthreads();
    for (int o = 1; o < 512; o <<= 1) {
        int tv = (tid >= o) ? sbuf[tid - o] : 0;
        __syncthreads();
        sbuf[tid] += tv;
        __syncthreads();
    }
    if (tid < NSLC) sbs[tid] = sbuf[tid] - v;
    if (tid == NSLC - 1) cnt_s = sbuf[tid];
    __syncthreads();
    const int cnt = min(cnt_s, CAPB);

    for (int idx = tid; idx < NSLC * SLICE; idx += 512) {
        int j = idx / SLICE, k = idx - j * SLICE;
        if (k < scl[j]) {
            int pos = sbs[j] + k;
            if (pos < CAPB)
                pairs[pos] = bpack[((size_t)j * NBKT + bkt) * SLICE + k];
        }
    }
    __syncthreads();

    for (int i = tid; i < cnt; i += 512)
        atomicAdd(&ncnt[(pairs[i] >> 16) & 127], 1);
    __syncthreads();
    v = (tid < 128) ? ncnt[tid] : 0;
    sbuf[tid] = v;
    __syncthreads();
    for (int o = 1; o < 128; o <<= 1) {
        int tv = (tid >= o && tid < 128) ? sbuf[tid - o] : 0;
        __syncthreads();
        if (tid < 128) sbuf[tid] += tv;
        __syncthreads();
    }
    if (tid < 128) {
        nrun[tid] = sbuf[tid] - v;
        const int n = bkt * 128 + tid;
        if (n < NN) {
            offs[n] = bkt * CAPB + nrun[tid];
            offe[n] = bkt * CAPB + nrun[tid] + v;
        }
    }
    __syncthreads();
    for (int i = tid; i < cnt; i += 512) {
        unsigned p = pairs[i];
        int nd = (p >> 16) & 127;
        int pos = atomicAdd(&lcur[nd], 1);
        csr[(size_t)bkt * CAPB + nrun[nd] + pos] = (ushort_t)(p & 0xffffu);
    }
}

// ================= K3: agg1 — mean of neighbor xb rows (wave = 4 edge-groups x 12 lanes) =================
__global__ __launch_bounds__(256) void k_agg1(const short* __restrict__ xb,
                                              const ushort_t* __restrict__ csr,
                                              const int* __restrict__ offs,
                                              const int* __restrict__ offe,
                                              short* __restrict__ m1b) {
    const int w = threadIdx.x >> 6;
    const int l = threadIdx.x & 63;
    const int n = blockIdx.x * 4 + w;
    if (n >= NN) return;
    const int eg = l / 12;
    const int c  = l % 12;
    const int b = offs[n], e = offe[n];
    const float4* xq = (const float4*)xb;   // row = 12 float4
    float acc[8];
#pragma unroll
    for (int k = 0; k < 8; ++k) acc[k] = 0.f;
    int i = (eg < 4) ? b + eg : e;
    for (; i + 12 < e; i += 16) {
        int s0 = csr[i], s1 = csr[i + 4], s2 = csr[i + 8], s3 = csr[i + 12];
        float4 v0 = xq[(size_t)s0 * 12 + c];
        float4 v1 = xq[(size_t)s1 * 12 + c];
        float4 v2 = xq[(size_t)s2 * 12 + c];
        float4 v3 = xq[(size_t)s3 * 12 + c];
        const unsigned* u0 = (const unsigned*)&v0;
        const unsigned* u1 = (const unsigned*)&v1;
        const unsigned* u2 = (const unsigned*)&v2;
        const unsigned* u3 = (const unsigned*)&v3;
#pragma unroll
        for (int jj = 0; jj < 4; ++jj) {
            acc[2 * jj]     += (bflo(u0[jj]) + bflo(u1[jj])) + (bflo(u2[jj]) + bflo(u3[jj]));
            acc[2 * jj + 1] += (bfhi(u0[jj]) + bfhi(u1[jj])) + (bfhi(u2[jj]) + bfhi(u3[jj]));
        }
    }
    for (; i < e; i += 4) {
        float4 v0 = xq[(size_t)csr[i] * 12 + c];
        const unsigned* u0 = (const unsigned*)&v0;
#pragma unroll
        for (int jj = 0; jj < 4; ++jj) {
            acc[2 * jj]     += bflo(u0[jj]);
            acc[2 * jj + 1] += bfhi(u0[jj]);
        }
    }
#pragma unroll
    for (int k = 0; k < 8; ++k) acc[k] += __shfl(acc[k], l + 24);
#pragma unroll
    for (int k = 0; k < 8; ++k) acc[k] += __shfl(acc[k], l + 12);
    if (l < 12) {
        const float inv = (e > b) ? 1.0f / (float)(e - b) : 0.0f;
        uint4 o;
        unsigned* op = (unsigned*)&o;
#pragma unroll
        for (int jj = 0; jj < 4; ++jj)
            op[jj] = (unsigned)(unsigned short)f2bf(acc[2 * jj] * inv)
                   | ((unsigned)(unsigned short)f2bf(acc[2 * jj + 1] * inv) << 16);
        ((uint4*)m1b)[(size_t)n * 12 + l] = o;
    }
}

// ================= K4: fused lin1+proj MFMA =================
#define SHP 136
__global__ __launch_bounds__(256) void k_linproj(const short* __restrict__ m1b,
                                                 const short* __restrict__ xb,
                                                 const short* __restrict__ Bt,
                                                 const float* __restrict__ b1,
                                                 const short* __restrict__ Bt2,
                                                 const float* __restrict__ b2,
                                                 short* __restrict__ zlb,
                                                 float* __restrict__ s) {
    __shared__ __align__(16) short sh[64][SHP];
    const int w = threadIdx.x >> 6;
    const int l = threadIdx.x & 63;
    const int lr = l & 15;
    const int lk = l >> 4;
    int row = blockIdx.x * 64 + w * 16 + lr;
    if (row >= NN) row = NN - 1;

    f32x4 acc[8];
#pragma unroll
    for (int nt = 0; nt < 8; ++nt) {
        float bv = b1[nt * 16 + lr];
        acc[nt] = (f32x4){bv, bv, bv, bv};
    }
    bf16x8 afr[6];
    {
        const bf16x8* am = (const bf16x8*)(m1b + (size_t)row * DIN);
        const bf16x8* ax = (const bf16x8*)(xb  + (size_t)row * DIN);
        afr[0] = am[lk];     afr[1] = am[4 + lk]; afr[2] = am[8 + lk];
        afr[3] = ax[lk];     afr[4] = ax[4 + lk]; afr[5] = ax[8 + lk];
    }
    const bf16x8* bt8 = (const bf16x8*)Bt;
#pragma unroll
    for (int st = 0; st < 6; ++st) {
#pragma unroll
        for (int nt = 0; nt < 8; ++nt) {
            bf16x8 bfr = bt8[(size_t)(nt * 16 + lr) * 24 + st * 4 + lk];
            acc[nt] = __builtin_amdgcn_mfma_f32_16x16x32_bf16(afr[st], bfr, acc[nt], 0, 0, 0);
        }
    }
    const int lrow0 = w * 16 + lk * 4;
#pragma unroll
    for (int r = 0; r < 4; ++r) {
#pragma unroll
        for (int nt = 0; nt < 8; ++nt)
            sh[lrow0 + r][nt * 16 + lr] = f2bf(fmaxf(acc[nt][r], 0.f));
    }
    __syncthreads();

    bf16x8 pafr[4];
#pragma unroll
    for (int st = 0; st < 4; ++st)
        pafr[st] = *(const bf16x8*)&sh[w * 16 + lr][st * 32 + lk * 8];

    f32x4 accz = (f32x4){0.f, 0.f, 0.f, 0.f};
    float bv = b2[lr];
    f32x4 accs = (f32x4){bv, bv, bv, bv};
    const bf16x8* b8 = (const bf16x8*)Bt2;
#pragma unroll
    for (int st = 0; st < 4; ++st) {
        bf16x8 bz = b8[(size_t)lr * 16 + st * 4 + lk];
        bf16x8 bs = b8[(size_t)(16 + lr) * 16 + st * 4 + lk];
        accz = __builtin_amdgcn_mfma_f32_16x16x32_bf16(pafr[st], bz, accz, 0, 0, 0);
        accs = __builtin_amdgcn_mfma_f32_16x16x32_bf16(pafr[st], bs, accs, 0, 0, 0);
    }
    const int orow0 = blockIdx.x * 64 + w * 16 + lk * 4;
#pragma unroll
    for (int r = 0; r < 4; ++r) {
        const int orow = orow0 + r;
        if (orow < NN) {
            zlb[(size_t)orow * DOUT + lr] = f2bf(accz[r]);
            s[(size_t)orow * DOUT + lr] = accs[r];
        }
    }
}

// ================= K5: agg2 + softmax =================
__global__ __launch_bounds__(256) void k_agg2(const short* __restrict__ zlb,
                                              const float* __restrict__ s,
                                              const ushort_t* __restrict__ csr,
                                              const int* __restrict__ offs,
                                              const int* __restrict__ offe,
                                              float* __restrict__ out) {
    const int w = threadIdx.x >> 6;
    const int lane = threadIdx.x & 63;
    const int n = blockIdx.x * 4 + w;
    if (n >= NN) return;
    const int b = offs[n], e = offe[n];
    const int ng = lane >> 2;
    const int sl = lane & 3;
    const uint2* z2 = (const uint2*)zlb;
    float4 acc = {0.f, 0.f, 0.f, 0.f};
    for (int i = b + ng; i < e; i += 16) {
        uint2 u = z2[(size_t)csr[i] * 4 + sl];
        acc.x += bflo(u.x);
        acc.y += bfhi(u.x);
        acc.z += bflo(u.y);
        acc.w += bfhi(u.y);
    }
#pragma unroll
    for (int o = 4; o <= 32; o <<= 1) {
        acc.x += __shfl_xor(acc.x, o);
        acc.y += __shfl_xor(acc.y, o);
        acc.z += __shfl_xor(acc.z, o);
        acc.w += __shfl_xor(acc.w, o);
    }
    const float inv = (e > b) ? 1.0f / (float)(e - b) : 0.0f;
    const float4 sv = ((const float4*)s)[(size_t)n * 4 + sl];
    float4 v;
    v.x = acc.x * inv + sv.x;
    v.y = acc.y * inv + sv.y;
    v.z = acc.z * inv + sv.z;
    v.w = acc.w * inv + sv.w;
    float mx = fmaxf(fmaxf(v.x, v.y), fmaxf(v.z, v.w));
    mx = fmaxf(mx, __shfl_xor(mx, 1));
    mx = fmaxf(mx, __shfl_xor(mx, 2));
    v.x = expf(v.x - mx); v.y = expf(v.y - mx);
    v.z = expf(v.z - mx); v.w = expf(v.w - mx);
    float sm = v.x + v.y + v.z + v.w;
    sm += __shfl_xor(sm, 1);
    sm += __shfl_xor(sm, 2);
    const float r = 1.0f / sm;
    v.x *= r; v.y *= r; v.z *= r; v.w *= r;
    if (ng == 0) ((float4*)out)[(size_t)n * 4 + sl] = v;
}

template <typename T>
static inline T* align_up(void* p, size_t a = 64) {
    return (T*)(((uintptr_t)p + (a - 1)) & ~(uintptr_t)(a - 1));
}

extern "C" void kernel_launch(void* const* d_in, const int* in_sizes, int n_in,
                              void* d_out, int out_size, void* d_ws, size_t ws_size,
                              hipStream_t stream) {
    const float* x   = (const float*)d_in[0];
    const int*   ei  = (const int*)d_in[1];
    const float* W1l = (const float*)d_in[2];
    const float* b1  = (const float*)d_in[3];
    const float* W1r = (const float*)d_in[4];
    const float* W2l = (const float*)d_in[5];
    const float* b2  = (const float*)d_in[6];
    const float* W2r = (const float*)d_in[7];
    float* out = (float*)d_out;

    // workspace layout
    unsigned* bpack = (unsigned*)d_ws;                                 // NSLC*NBKT*SLICE (~14.7MB)
    int* scnt     = (int*)(bpack + (size_t)NSLC * NBKT * SLICE);       // NSLC*NBKT
    float* s      = (float*)(scnt + (size_t)NSLC * NBKT);              // NN*DOUT
    int* offs     = (int*)(s + (size_t)NN * DOUT);                     // NN
    int* offe     = offs + NN;                                         // NN
    ushort_t* csr = (ushort_t*)align_up<short>(offe + NN);             // NBKT*CAPB (2B)
    short* xb     = (short*)csr + (size_t)NBKT * CAPB;                 // NN*DIN
    short* m1b    = xb + (size_t)NN * DIN;                             // NN*DIN
    short* zlb    = m1b + (size_t)NN * DIN;                            // NN*DOUT
    short* Bt     = zlb + (size_t)NN * DOUT;                           // DH*192
    short* Bt2    = Bt + (size_t)DH * 192;                             // 32*DH

    k_prep<<<XB_BLOCKS + WC_BLOCKS + NSLC, 512, 0, stream>>>(
        x, W1l, W1r, W2l, W2r, ei, xb, Bt, Bt2, bpack, scnt);
    k_build<<<NBKT, 512, 0, stream>>>(bpack, scnt, offs, offe, csr);
    k_agg1<<<(NN + 3) / 4, 256, 0, stream>>>(xb, csr, offs, offe, m1b);
    k_linproj<<<(NN + 63) / 64, 256, 0, stream>>>(m1b, xb, Bt, b1, Bt2, b2, zlb, s);
    k_agg2<<<(NN + 3) / 4, 256, 0, stream>>>(zlb, s, csr, offs, offe, out);
}